// Round 17
// baseline (694.003 us; speedup 1.0000x reference)
//
#include <hip/hip_runtime.h>
#include <hip/hip_bf16.h>
#include <hip/hip_fp16.h>
#include <cstddef>
#include <cstdint>

#define N_NODES 20000
#define N_EDGES 100000
#define N_BATCH 512

#define EPB 96   // edges per block
#define TS 6     // 16-row M-subtiles (V0)
#define ECAP 100032  // slot capacity (divisible by 96)

typedef __attribute__((ext_vector_type(8))) short ushort8_t;
typedef __attribute__((ext_vector_type(8))) _Float16 f16x8;
typedef __attribute__((ext_vector_type(4))) float f32x4;
typedef __attribute__((ext_vector_type(16))) float f32x16;

union F16x8U { f16x8 v; unsigned int u[4]; };

__device__ __forceinline__ float sigmoidf_(float x) { return 1.f / (1.f + expf(-x)); }
__device__ __forceinline__ unsigned short f2h(float x) {
    return __half_as_ushort(__float2half(x));
}
__device__ __forceinline__ float h2f(unsigned short s) {
    return __half2float(__ushort_as_half(s));
}

// ============ prep1: lin0 + bsw16 pack + bsw32 pack + dst histogram ============
#define LIN0_BLOCKS 5000   // N*64/256
#define BSW_BLOCKS 258
#define BSW32_BLOCKS 258
#define CNT_BLOCKS 391     // ceil(E/256)

__global__ __launch_bounds__(256) void prep1_kernel(
        const float* __restrict__ x, const float* __restrict__ l0w, const float* __restrict__ l0b,
        const float* __restrict__ w2, const float* __restrict__ b2,
        const int* __restrict__ ei,
        float* __restrict__ out, unsigned short* __restrict__ bsw16,
        unsigned short* __restrict__ bsw32, int* __restrict__ cnt, int E) {
    int bid = blockIdx.x, tid = threadIdx.x;
    if (bid < LIN0_BLOCKS) {
        int idx = bid * 256 + tid;   // n*64 + j
        int n = idx >> 6, j = idx & 63;
        float acc = l0b[j];
#pragma unroll
        for (int i = 0; i < 16; i++) acc += x[n * 16 + i] * l0w[i * 64 + j];
        out[idx] = fmaxf(acc, 0.f);
    } else if (bid < LIN0_BLOCKS + BSW_BLOCKS) {
        int idx = (bid - LIN0_BLOCKS) * 256 + tid;
        if (idx < 66048) {
            // 16x16x32 layout: idx = (ks*8 + st*4 + oc)*64 + l  (ks = k)
            int l = idx & 63, oc = (idx >> 6) & 3, ks = idx >> 8;
            int o = oc * 16 + (l & 15);
            int kap0 = ks * 32 + 8 * (l >> 4);
#pragma unroll
            for (int j = 0; j < 8; ++j) {
                int kap = kap0 + j;
                int k = kap >> 6, i = kap & 63;
                float v = (k < 128) ? w2[(size_t)k * 4096 + i * 64 + o] : b2[i * 64 + o];
                bsw16[(size_t)idx * 8 + j] = f2h(v);
            }
        }
    } else if (bid < LIN0_BLOCKS + BSW_BLOCKS + BSW32_BLOCKS) {
        int idx = (bid - LIN0_BLOCKS - BSW_BLOCKS) * 256 + tid;
        if (idx < 66048) {
            // 32x32x16 layout: idx = (k*8 + c*2 + oc)*64 + l
            int l = idx & 63, oc = (idx >> 6) & 1, c = (idx >> 7) & 3, k = idx >> 9;
            int o = oc * 32 + (l & 31);
            int i0 = c * 16 + 8 * (l >> 5);
#pragma unroll
            for (int j = 0; j < 8; ++j) {
                int i = i0 + j;
                float v = (k < 128) ? w2[(size_t)k * 4096 + i * 64 + o] : b2[i * 64 + o];
                bsw32[(size_t)idx * 8 + j] = f2h(v);
            }
        }
    } else {
        int e = (bid - LIN0_BLOCKS - BSW_BLOCKS - BSW32_BLOCKS) * 256 + tid;
        if (e < E) atomicAdd(&cnt[ei[E + e]], 1);
    }
}

// ============ prep2: exclusive scan of cnt -> cstart, cursor; deg float ============
__global__ __launch_bounds__(1024) void scan_kernel(const int* __restrict__ cnt,
                                                    int* __restrict__ cstart,
                                                    int* __restrict__ cursor,
                                                    float* __restrict__ degf, int n) {
    __shared__ int part[1024];
    int t = threadIdx.x;
    int base = t * 20;
    int loc[20];
    int s = 0;
#pragma unroll
    for (int i = 0; i < 20; ++i) {
        int idx = base + i;
        int c = (idx < n) ? cnt[idx] : 0;
        loc[i] = s;
        s += c;
    }
    part[t] = s;
    __syncthreads();
    for (int off = 1; off < 1024; off <<= 1) {
        int v = (t >= off) ? part[t - off] : 0;
        __syncthreads();
        part[t] += v;
        __syncthreads();
    }
    int tb = part[t] - s;   // exclusive base
#pragma unroll
    for (int i = 0; i < 20; ++i) {
        int idx = base + i;
        if (idx < n) {
            int b0 = tb + loc[i];
            cstart[idx] = b0;
            cursor[idx] = b0;
            degf[idx] = (float)cnt[idx];
        }
    }
}

// ============ prep3: bucket-place edges sorted by dst (also permutes edge_attr) ====
__global__ void place_kernel(const int* __restrict__ ei, const float* __restrict__ ea,
                             int* __restrict__ cursor,
                             int* __restrict__ src_s, float* __restrict__ ea_s, int E) {
    int e = blockIdx.x * 256 + threadIdx.x;
    if (e < E) {
        int dst = ei[E + e];
        int slot = atomicAdd(&cursor[dst], 1);
        src_s[slot] = ei[e];
        const float4* s = (const float4*)(ea + (size_t)e * 8);
        float4 a = s[0], b = s[1];
        float4* d = (float4*)(ea_s + (size_t)slot * 8);
        d[0] = a; d[1] = b;
    }
}

// ============ fused NNConv message — MFMA shape A/B template =====================
// SHAPE 0: 16x16x32 (R14 exact). SHAPE 1: 32x32x16 (half the MFMA instructions).
// Both: in-kernel edge MLP into hs16, k-split across 4 waves, plain fp16 slab stores.
template<int SHAPE>
__global__ __launch_bounds__(256, 2) void msg_mfma(const float* __restrict__ out,
                                                   const float* __restrict__ ea_s,
                                                   const float* __restrict__ w1g,
                                                   const float* __restrict__ b1g,
                                                   const unsigned short* __restrict__ bsw,
                                                   const int* __restrict__ src_s,
                                                   unsigned short* __restrict__ msgp, int E) {
    __shared__ __align__(16) unsigned short hs16[128 * EPB];   // 24.6 KB
    __shared__ __align__(16) float w1l[8 * 128];               // 4 KB
    __shared__ __align__(16) float b1l[128];
    const int tid = threadIdx.x;
    const int w = tid >> 6, l = tid & 63;
    const int e0 = blockIdx.x * EPB;
    const int r16 = l & 15, q = l >> 4;
    const int l31 = l & 31, hi = l >> 5;

    // stage W1 + b1 into LDS
    {
        f32x4 v = *(const f32x4*)&w1g[tid * 4];
        *(f32x4*)&w1l[tid * 4] = v;
        if (tid < 32) *(f32x4*)&b1l[tid * 4] = *(const f32x4*)&b1g[tid * 4];
    }

    __syncthreads();   // w1l/b1l ready

    // in-kernel edge MLP: thread t<192 computes h[e'=t>>1][koff..koff+64)
    if (tid < 192) {
        int ep = tid >> 1;
        int koff = (tid & 1) * 64;
        int e = e0 + ep;
        bool v = e < E;
        float ear[8];
        const float* earow = ea_s + (size_t)(v ? e : 0) * 8;
#pragma unroll
        for (int i = 0; i < 8; ++i) ear[i] = earow[i];
#pragma unroll
        for (int kv = 0; kv < 16; ++kv) {
            int k = koff + kv * 4;
            f32x4 a = *(const f32x4*)&b1l[k];
#pragma unroll
            for (int i = 0; i < 8; ++i) {
                f32x4 wv = *(const f32x4*)&w1l[i * 128 + k];
                a += ear[i] * wv;
            }
#pragma unroll
            for (int jj = 0; jj < 4; ++jj)
                hs16[(k + jj) * EPB + ep] = v ? f2h(fmaxf(a[jj], 0.f)) : (unsigned short)0;
        }
    }

    const f16x8* bp = (const f16x8*)bsw;

    if constexpr (SHAPE == 0) {
        // ---------------- V0: 16x16x32 (R14 exact) ----------------
        f16x8 sfrag[TS][2];
#pragma unroll
        for (int t = 0; t < TS; ++t) {
            int e = e0 + t * 16 + r16;
            int src = (e < E) ? src_s[e] : 0;
            const f32x4* p = (const f32x4*)(out + (size_t)src * 64);
#pragma unroll
            for (int st = 0; st < 2; ++st) {
                f16x8 f = {};
                if (e < E) {
                    f32x4 a = p[st * 8 + q * 2], b = p[st * 8 + q * 2 + 1];
#pragma unroll
                    for (int j = 0; j < 4; ++j) { f[j] = (_Float16)a[j]; f[4 + j] = (_Float16)b[j]; }
                }
                sfrag[t][st] = f;
            }
        }

        f16x8 bfA[8], bfB[8];
#pragma unroll
        for (int i = 0; i < 8; ++i) bfA[i] = bp[((w * 8 + i) << 6) + l];

        __syncthreads();   // hs16 ready

        f32x4 acc[TS][4] = {};

#define MSG_BODY16(K, BF)                                                      \
    {                                                                          \
        _Pragma("unroll")                                                      \
        for (int t = 0; t < TS; ++t) {                                         \
            unsigned int hu = hs16[(K) * EPB + t * 16 + r16];                  \
            _Pragma("unroll")                                                  \
            for (int st = 0; st < 2; ++st) {                                   \
                F16x8U s_, a_;                                                 \
                s_.v = sfrag[t][st];                                           \
                asm("v_pk_mul_f16 %0, %1, %2 op_sel:[0,0] op_sel_hi:[0,1]"     \
                    : "=v"(a_.u[0]) : "v"(hu), "v"(s_.u[0]));                  \
                asm("v_pk_mul_f16 %0, %1, %2 op_sel:[0,0] op_sel_hi:[0,1]"     \
                    : "=v"(a_.u[1]) : "v"(hu), "v"(s_.u[1]));                  \
                asm("v_pk_mul_f16 %0, %1, %2 op_sel:[0,0] op_sel_hi:[0,1]"     \
                    : "=v"(a_.u[2]) : "v"(hu), "v"(s_.u[2]));                  \
                asm("v_pk_mul_f16 %0, %1, %2 op_sel:[0,0] op_sel_hi:[0,1]"     \
                    : "=v"(a_.u[3]) : "v"(hu), "v"(s_.u[3]));                  \
                _Pragma("unroll")                                              \
                for (int oc = 0; oc < 4; ++oc)                                 \
                    acc[t][oc] = __builtin_amdgcn_mfma_f32_16x16x32_f16(       \
                        a_.v, BF[st * 4 + oc], acc[t][oc], 0, 0, 0);           \
            }                                                                  \
        }                                                                      \
    }

#pragma unroll 1
        for (int kk = 0; kk < 16; ++kk) {
            int k1 = w + kk * 8;
            int k2 = k1 + 4;
#pragma unroll
            for (int i = 0; i < 8; ++i) bfB[i] = bp[((k2 * 8 + i) << 6) + l];
            MSG_BODY16(k1, bfA);
            if (kk < 15) {
                int k3 = k1 + 8;
#pragma unroll
                for (int i = 0; i < 8; ++i) bfA[i] = bp[((k3 * 8 + i) << 6) + l];
            }
            MSG_BODY16(k2, bfB);
        }
#undef MSG_BODY16

        // bias pseudo-slot k=128 (h = 1), wave 0 only
        if (w == 0) {
#pragma unroll
            for (int i = 0; i < 8; ++i) bfA[i] = bp[((128 * 8 + i) << 6) + l];
#pragma unroll
            for (int t = 0; t < TS; ++t)
#pragma unroll
                for (int st = 0; st < 2; ++st)
#pragma unroll
                    for (int oc = 0; oc < 4; ++oc)
                        acc[t][oc] = __builtin_amdgcn_mfma_f32_16x16x32_f16(
                            sfrag[t][st], bfA[st * 4 + oc], acc[t][oc], 0, 0, 0);
        }

        unsigned short* slab = msgp + (size_t)w * ECAP * 64;
#pragma unroll
        for (int t = 0; t < TS; ++t) {
#pragma unroll
            for (int r = 0; r < 4; ++r) {
                int e = e0 + t * 16 + q * 4 + r;
                if (e < E) {
                    unsigned short* row = slab + (size_t)e * 64 + r16;
                    row[0]  = f2h(acc[t][0][r]);
                    row[16] = f2h(acc[t][1][r]);
                    row[32] = f2h(acc[t][2][r]);
                    row[48] = f2h(acc[t][3][r]);
                }
            }
        }
    } else {
        // ---------------- V1: 32x32x16 (half the MFMA count) ----------------
        // lane owns edge e = e0 + t*32 + l31; sfr[t][c][j] = s_e[c*16 + 8*hi + j]
        f16x8 sfr[3][4];
#pragma unroll
        for (int t = 0; t < 3; ++t) {
            int e = e0 + t * 32 + l31;
            int src = (e < E) ? src_s[e] : 0;
            const f32x4* p = (const f32x4*)(out + (size_t)src * 64);
#pragma unroll
            for (int c = 0; c < 4; ++c) {
                f16x8 f = {};
                if (e < E) {
                    f32x4 a = p[c * 4 + 2 * hi], b = p[c * 4 + 2 * hi + 1];
#pragma unroll
                    for (int j = 0; j < 4; ++j) { f[j] = (_Float16)a[j]; f[4 + j] = (_Float16)b[j]; }
                }
                sfr[t][c] = f;
            }
        }

        f16x8 bfA[8], bfB[8];
#pragma unroll
        for (int i = 0; i < 8; ++i) bfA[i] = bp[((w * 8 + i) << 6) + l];

        __syncthreads();   // hs16 ready

        f32x16 acc[3][2] = {};

#define MSG_BODY32(K, BF)                                                      \
    {                                                                          \
        _Pragma("unroll")                                                      \
        for (int t = 0; t < 3; ++t) {                                          \
            unsigned int hu = hs16[(K) * EPB + t * 32 + l31];                  \
            _Pragma("unroll")                                                  \
            for (int c = 0; c < 4; ++c) {                                      \
                F16x8U s_, a_;                                                 \
                s_.v = sfr[t][c];                                              \
                asm("v_pk_mul_f16 %0, %1, %2 op_sel:[0,0] op_sel_hi:[0,1]"     \
                    : "=v"(a_.u[0]) : "v"(hu), "v"(s_.u[0]));                  \
                asm("v_pk_mul_f16 %0, %1, %2 op_sel:[0,0] op_sel_hi:[0,1]"     \
                    : "=v"(a_.u[1]) : "v"(hu), "v"(s_.u[1]));                  \
                asm("v_pk_mul_f16 %0, %1, %2 op_sel:[0,0] op_sel_hi:[0,1]"     \
                    : "=v"(a_.u[2]) : "v"(hu), "v"(s_.u[2]));                  \
                asm("v_pk_mul_f16 %0, %1, %2 op_sel:[0,0] op_sel_hi:[0,1]"     \
                    : "=v"(a_.u[3]) : "v"(hu), "v"(s_.u[3]));                  \
                acc[t][0] = __builtin_amdgcn_mfma_f32_32x32x16_f16(            \
                    a_.v, BF[c * 2 + 0], acc[t][0], 0, 0, 0);                  \
                acc[t][1] = __builtin_amdgcn_mfma_f32_32x32x16_f16(            \
                    a_.v, BF[c * 2 + 1], acc[t][1], 0, 0, 0);                  \
            }                                                                  \
        }                                                                      \
    }

#pragma unroll 1
        for (int kk = 0; kk < 16; ++kk) {
            int k1 = w + kk * 8;
            int k2 = k1 + 4;
#pragma unroll
            for (int i = 0; i < 8; ++i) bfB[i] = bp[((k2 * 8 + i) << 6) + l];
            MSG_BODY32(k1, bfA);
            if (kk < 15) {
                int k3 = k1 + 8;
#pragma unroll
                for (int i = 0; i < 8; ++i) bfA[i] = bp[((k3 * 8 + i) << 6) + l];
            }
            MSG_BODY32(k2, bfB);
        }
#undef MSG_BODY32

        // bias pseudo-slot k=128 (h = 1), wave 0 only
        if (w == 0) {
#pragma unroll
            for (int i = 0; i < 8; ++i) bfA[i] = bp[((128 * 8 + i) << 6) + l];
#pragma unroll
            for (int t = 0; t < 3; ++t)
#pragma unroll
                for (int c = 0; c < 4; ++c) {
                    acc[t][0] = __builtin_amdgcn_mfma_f32_32x32x16_f16(
                        sfr[t][c], bfA[c * 2 + 0], acc[t][0], 0, 0, 0);
                    acc[t][1] = __builtin_amdgcn_mfma_f32_32x32x16_f16(
                        sfr[t][c], bfA[c * 2 + 1], acc[t][1], 0, 0, 0);
                }
        }

        // C layout (32x32): col = oc*32 + l31, row = (r&3) + 8*(r>>2) + 4*hi
        unsigned short* slab = msgp + (size_t)w * ECAP * 64;
#pragma unroll
        for (int t = 0; t < 3; ++t)
#pragma unroll
            for (int oc = 0; oc < 2; ++oc)
#pragma unroll
                for (int r = 0; r < 16; ++r) {
                    int e = e0 + t * 32 + (r & 3) + 8 * (r >> 2) + 4 * hi;
                    if (e < E)
                        slab[(size_t)e * 64 + oc * 32 + l31] = f2h(acc[t][oc][r]);
                }
    }
}

// ---- gru: aggregate msgp over dst run; m = relu(msum/deg + out@root_w + root_b); GRU
__global__ __launch_bounds__(256) void gru_kernel(float* __restrict__ out,
                                                  const unsigned short* __restrict__ msgp,
                                                  const int* __restrict__ cstart,
                                                  const int* __restrict__ cnt,
                                                  const float* __restrict__ deg,
                                                  const float* __restrict__ root_w,
                                                  const float* __restrict__ root_b,
                                                  const float* __restrict__ wih,
                                                  const float* __restrict__ whh,
                                                  const float* __restrict__ bih,
                                                  const float* __restrict__ bhh) {
    int w = threadIdx.x >> 6, j = threadIdx.x & 63;
    int n = blockIdx.x * 4 + w;            // N divisible by 4
    __shared__ float s_o[4][64];
    __shared__ float s_m[4][64];
    s_o[w][j] = out[(size_t)n * 64 + j];
    __syncthreads();

    // aggregate messages: sum 4 k-partial slabs over this node's slot run
    float msum = 0.f;
    {
        int base = cstart[n], c = cnt[n];
        for (int s2 = 0; s2 < c; ++s2) {
            size_t slot = (size_t)(base + s2) * 64 + j;
            float a0 = h2f(msgp[slot]);
            float a1 = h2f(msgp[(size_t)ECAP * 64 + slot]);
            float a2 = h2f(msgp[2 * (size_t)ECAP * 64 + slot]);
            float a3 = h2f(msgp[3 * (size_t)ECAP * 64 + slot]);
            msum += (a0 + a1) + (a2 + a3);
        }
    }
    float d = deg[n]; if (d < 1.f) d = 1.f;
    float mv = msum / d + root_b[j];
#pragma unroll 8
    for (int i = 0; i < 64; i++) mv += s_o[w][i] * root_w[i * 64 + j];
    mv = fmaxf(mv, 0.f);
    s_m[w][j] = mv;
    __syncthreads();
    float gi_r = bih[j], gi_z = bih[64 + j], gi_n = bih[128 + j];
    float gh_r = bhh[j], gh_z = bhh[64 + j], gh_n = bhh[128 + j];
#pragma unroll 4
    for (int i = 0; i < 64; i++) {
        float m = s_m[w][i], hv = s_o[w][i];
        gi_r += m * wih[i * 192 + j];
        gi_z += m * wih[i * 192 + 64 + j];
        gi_n += m * wih[i * 192 + 128 + j];
        gh_r += hv * whh[i * 192 + j];
        gh_z += hv * whh[i * 192 + 64 + j];
        gh_n += hv * whh[i * 192 + 128 + j];
    }
    float r = sigmoidf_(gi_r + gh_r);
    float z = sigmoidf_(gi_z + gh_z);
    float nn = tanhf(gi_n + r * gh_n);
    float hnew = (1.f - z) * nn + z * s_o[w][j];
    out[(size_t)n * 64 + j] = hnew;
}

// ============ fused Set2Set (3 iterations) + output head, one block per graph ======
__global__ __launch_bounds__(256) void s2s_final(const float* __restrict__ out,
                                                 const int* __restrict__ batch,
                                                 const float* __restrict__ wih,
                                                 const float* __restrict__ whh,
                                                 const float* __restrict__ bih,
                                                 const float* __restrict__ bhh,
                                                 const float* __restrict__ w1,
                                                 const float* __restrict__ b1,
                                                 const float* __restrict__ w2,
                                                 const float* __restrict__ b2,
                                                 float* __restrict__ y, int N) {
    int b = blockIdx.x;
    int tid = threadIdx.x;
    int gate = tid >> 6, j = tid & 63;
    __shared__ float s_qs[128];
    __shared__ float s_g[4][64];
    __shared__ float s_h[64];
    __shared__ float s_c[64];
    __shared__ int s_lo, s_hi;
    __shared__ float s_red[4];
    __shared__ float s_rv[4][64];

    if (tid < 128) s_qs[tid] = 0.f;
    if (gate == 2) s_h[j] = 0.f;
    if (gate == 3) s_c[j] = 0.f;
    if (tid == 0) {
        int lo = 0, hi = N;
        while (lo < hi) { int mid = (lo + hi) >> 1; if (batch[mid] < b) lo = mid + 1; else hi = mid; }
        s_lo = lo;
        int lo2 = lo, hi2 = N;
        while (lo2 < hi2) { int mid = (lo2 + hi2) >> 1; if (batch[mid] < b + 1) lo2 = mid + 1; else hi2 = mid; }
        s_hi = lo2;
    }
    __syncthreads();

    for (int it = 0; it < 3; ++it) {
        float g = bih[gate * 64 + j] + bhh[gate * 64 + j];
#pragma unroll 4
        for (int i = 0; i < 128; ++i) g += s_qs[i] * wih[i * 256 + gate * 64 + j];
#pragma unroll 4
        for (int i = 0; i < 64; ++i) g += s_h[i] * whh[i * 256 + gate * 64 + j];
        s_g[gate][j] = g;
        __syncthreads();
        if (gate == 0) {
            float c = sigmoidf_(s_g[1][j]) * s_c[j] + sigmoidf_(s_g[0][j]) * tanhf(s_g[2][j]);
            float h = sigmoidf_(s_g[3][j]) * tanhf(c);
            s_c[j] = c;
            s_h[j] = h;
            s_qs[j] = h;
        }
        __syncthreads();

        int lo = s_lo, hi = s_hi;
        float wmax = -3.402823e38f;
        for (int n = lo + gate; n < hi; n += 4) {
            float p = out[(size_t)n * 64 + j] * s_h[j];
#pragma unroll
            for (int d = 32; d >= 1; d >>= 1) p += __shfl_xor(p, d);
            wmax = fmaxf(wmax, p);
        }
        if (j == 0) s_red[gate] = wmax;
        __syncthreads();
        float m = fmaxf(fmaxf(s_red[0], s_red[1]), fmaxf(s_red[2], s_red[3]));
        __syncthreads();
        float ssum = 0.f, rv = 0.f;
        for (int n = lo + gate; n < hi; n += 4) {
            float xv = out[(size_t)n * 64 + j];
            float p = xv * s_h[j];
#pragma unroll
            for (int d = 32; d >= 1; d >>= 1) p += __shfl_xor(p, d);
            float a = expf(p - m);
            ssum += a;
            rv += a * xv;
        }
        if (j == 0) s_red[gate] = ssum;
        s_rv[gate][j] = rv;
        __syncthreads();
        if (gate == 0) {
            float S = s_red[0] + s_red[1] + s_red[2] + s_red[3];
            float r = s_rv[0][j] + s_rv[1][j] + s_rv[2][j] + s_rv[3][j];
            s_qs[64 + j] = (S > 0.f) ? r / S : 0.f;
        }
        __syncthreads();
    }

    if (gate == 0) {
        float tv = b1[j];
#pragma unroll 4
        for (int i = 0; i < 128; ++i) tv += s_qs[i] * w1[i * 64 + j];
        tv = fmaxf(tv, 0.f);
        float p = tv * w2[j];
#pragma unroll
        for (int d = 32; d >= 1; d >>= 1) p += __shfl_xor(p, d);
        if (j == 0) y[b] = p + b2[0];
    }
}

extern "C" void kernel_launch(void* const* d_in, const int* in_sizes, int n_in,
                              void* d_out, int out_size, void* d_ws, size_t ws_size,
                              hipStream_t stream) {
    const int N = N_NODES, E = N_EDGES, B = N_BATCH;
    const float* x       = (const float*)d_in[0];
    const int*   ei      = (const int*)d_in[1];
    const float* ea      = (const float*)d_in[2];
    const int*   batch   = (const int*)d_in[3];
    const float* lin0_w  = (const float*)d_in[4];
    const float* lin0_b  = (const float*)d_in[5];
    const float* nn1_w   = (const float*)d_in[6];
    const float* nn1_b   = (const float*)d_in[7];
    const float* nn2_w   = (const float*)d_in[8];
    const float* nn2_b   = (const float*)d_in[9];
    const float* root_w  = (const float*)d_in[10];
    const float* root_b  = (const float*)d_in[11];
    const float* gru_wih = (const float*)d_in[12];
    const float* gru_whh = (const float*)d_in[13];
    const float* gru_bih = (const float*)d_in[14];
    const float* gru_bhh = (const float*)d_in[15];
    const float* lstm_wih = (const float*)d_in[16];
    const float* lstm_whh = (const float*)d_in[17];
    const float* lstm_bih = (const float*)d_in[18];
    const float* lstm_bhh = (const float*)d_in[19];
    const float* lin1_w  = (const float*)d_in[20];
    const float* lin1_b  = (const float*)d_in[21];
    const float* lin2_w  = (const float*)d_in[22];
    const float* lin2_b  = (const float*)d_in[23];
    float* y = (float*)d_out;

    char* ws = (char*)d_ws;
    size_t off = 0;
    auto alloc = [&](size_t bytes) { void* p = ws + off; off = (off + bytes + 255) & ~(size_t)255; return p; };
    unsigned short* bsw16 = (unsigned short*)alloc((size_t)66048 * 8 * 2);   // 1.06 MB fp16
    unsigned short* bsw32 = (unsigned short*)alloc((size_t)66048 * 8 * 2);   // 1.06 MB fp16
    unsigned short* msgp  = (unsigned short*)alloc((size_t)4 * ECAP * 64 * 2);// 51.2 MB fp16
    float* ea_s   = (float*)alloc((size_t)ECAP * 8 * 4);                     // 3.2 MB (sorted)
    float* out    = (float*)alloc((size_t)N * 64 * 4);                       // 5.12 MB
    float* deg    = (float*)alloc((size_t)N * 4);
    int*   cnt    = (int*)alloc((size_t)N * 4);
    int*   cstart = (int*)alloc((size_t)N * 4);
    int*   cursor = (int*)alloc((size_t)N * 4);
    int*   src_s  = (int*)alloc((size_t)E * 4);

    hipMemsetAsync(cnt, 0, (size_t)N * 4, stream);

    prep1_kernel<<<LIN0_BLOCKS + BSW_BLOCKS + BSW32_BLOCKS + CNT_BLOCKS, 256, 0, stream>>>(
        x, lin0_w, lin0_b, nn2_w, nn2_b, ei, out, bsw16, bsw32, cnt, E);
    scan_kernel<<<1, 1024, 0, stream>>>(cnt, cstart, cursor, deg, N);
    place_kernel<<<(E + 255) / 256, 256, 0, stream>>>(ei, ea, cursor, src_s, ea_s, E);

    // step 0: V0 control (16x16x32, R14 exact)
    msg_mfma<0><<<(E + EPB - 1) / EPB, 256, 0, stream>>>(out, ea_s, nn1_w, nn1_b,
                                                         bsw16, src_s, msgp, E);
    gru_kernel<<<N / 4, 256, 0, stream>>>(out, msgp, cstart, cnt, deg, root_w, root_b,
                                          gru_wih, gru_whh, gru_bih, gru_bhh);
    // steps 1,2: V1 (32x32x16), two samples
    for (int step = 1; step < 3; ++step) {
        msg_mfma<1><<<(E + EPB - 1) / EPB, 256, 0, stream>>>(out, ea_s, nn1_w, nn1_b,
                                                             bsw32, src_s, msgp, E);
        gru_kernel<<<N / 4, 256, 0, stream>>>(out, msgp, cstart, cnt, deg, root_w, root_b,
                                              gru_wih, gru_whh, gru_bih, gru_bhh);
    }

    s2s_final<<<B, 256, 0, stream>>>(out, batch, lstm_wih, lstm_whh, lstm_bih, lstm_bhh,
                                     lin1_w, lin1_b, lin2_w, lin2_b, y, N);
}

// Round 18
// 682.735 us; speedup vs baseline: 1.0165x; 1.0165x over previous
//
#include <hip/hip_runtime.h>
#include <hip/hip_bf16.h>
#include <hip/hip_fp16.h>
#include <cstddef>
#include <cstdint>

#define N_NODES 20000
#define N_EDGES 100000
#define N_BATCH 512

#define EPB 96   // edges per block
#define TS 6     // 16-row M-subtiles per block
#define ECAP 100032  // slot capacity (divisible by 96)

typedef __attribute__((ext_vector_type(8))) short ushort8_t;
typedef __attribute__((ext_vector_type(8))) _Float16 f16x8;
typedef __attribute__((ext_vector_type(4))) float f32x4;

union F16x8U { f16x8 v; unsigned int u[4]; };

__device__ __forceinline__ float sigmoidf_(float x) { return 1.f / (1.f + expf(-x)); }
__device__ __forceinline__ unsigned short f2h(float x) {
    return __half_as_ushort(__float2half(x));
}
__device__ __forceinline__ float h2f(unsigned short s) {
    return __half2float(__ushort_as_half(s));
}

// ============ prep1: lin0 + bsw pack + dst histogram ============
#define LIN0_BLOCKS 5000  // N*64/256
#define BSW_BLOCKS 258
#define CNT_BLOCKS 391    // ceil(E/256)

__global__ __launch_bounds__(256) void prep1_kernel(
        const float* __restrict__ x, const float* __restrict__ l0w, const float* __restrict__ l0b,
        const float* __restrict__ w2, const float* __restrict__ b2,
        const int* __restrict__ ei,
        float* __restrict__ out, unsigned short* __restrict__ bsw,
        int* __restrict__ cnt, int E) {
    int bid = blockIdx.x, tid = threadIdx.x;
    if (bid < LIN0_BLOCKS) {
        int idx = bid * 256 + tid;   // n*64 + j
        int n = idx >> 6, j = idx & 63;
        float acc = l0b[j];
#pragma unroll
        for (int i = 0; i < 16; i++) acc += x[n * 16 + i] * l0w[i * 64 + j];
        out[idx] = fmaxf(acc, 0.f);
    } else if (bid < LIN0_BLOCKS + BSW_BLOCKS) {
        int idx = (bid - LIN0_BLOCKS) * 256 + tid;
        if (idx < 66048) {
            int l = idx & 63, oc = (idx >> 6) & 3, ks = idx >> 8;
            int o = oc * 16 + (l & 15);
            int kap0 = ks * 32 + 8 * (l >> 4);
#pragma unroll
            for (int j = 0; j < 8; ++j) {
                int kap = kap0 + j;
                int k = kap >> 6, i = kap & 63;
                float v = (k < 128) ? w2[(size_t)k * 4096 + i * 64 + o] : b2[i * 64 + o];
                bsw[(size_t)idx * 8 + j] = f2h(v);
            }
        }
    } else {
        int e = (bid - LIN0_BLOCKS - BSW_BLOCKS) * 256 + tid;
        if (e < E) atomicAdd(&cnt[ei[E + e]], 1);
    }
}

// ============ prep2: exclusive scan of cnt -> cstart, cursor; deg float ============
__global__ __launch_bounds__(1024) void scan_kernel(const int* __restrict__ cnt,
                                                    int* __restrict__ cstart,
                                                    int* __restrict__ cursor,
                                                    float* __restrict__ degf, int n) {
    __shared__ int part[1024];
    int t = threadIdx.x;
    int base = t * 20;
    int loc[20];
    int s = 0;
#pragma unroll
    for (int i = 0; i < 20; ++i) {
        int idx = base + i;
        int c = (idx < n) ? cnt[idx] : 0;
        loc[i] = s;
        s += c;
    }
    part[t] = s;
    __syncthreads();
    for (int off = 1; off < 1024; off <<= 1) {
        int v = (t >= off) ? part[t - off] : 0;
        __syncthreads();
        part[t] += v;
        __syncthreads();
    }
    int tb = part[t] - s;   // exclusive base
#pragma unroll
    for (int i = 0; i < 20; ++i) {
        int idx = base + i;
        if (idx < n) {
            int b0 = tb + loc[i];
            cstart[idx] = b0;
            cursor[idx] = b0;
            degf[idx] = (float)cnt[idx];
        }
    }
}

// ============ prep3: bucket-place edges sorted by dst (also permutes edge_attr) ====
__global__ void place_kernel(const int* __restrict__ ei, const float* __restrict__ ea,
                             int* __restrict__ cursor,
                             int* __restrict__ src_s, float* __restrict__ ea_s, int E) {
    int e = blockIdx.x * 256 + threadIdx.x;
    if (e < E) {
        int dst = ei[E + e];
        int slot = atomicAdd(&cursor[dst], 1);
        src_s[slot] = ei[e];
        const float4* s = (const float4*)(ea + (size_t)e * 8);
        float4 a = s[0], b = s[1];
        float4* d = (float4*)(ea_s + (size_t)slot * 8);
        d[0] = a; d[1] = b;
    }
}

// ============ fused NNConv message, fp16 MFMA 16x16x32, dst-sorted edges ============
// In-kernel edge MLP: h = relu(ea_s @ W1 + b1) computed into LDS (no hb buffer).
// msg[e,:] = sum_k (h[e,k]*s_e) @ B_k + s_e @ b2v  (bias = pseudo-slot k==128, h=1)
// 4 waves/block, k split across waves. Wave w stores its fp16 k-partial into the
// interleaved layout msgp[slot][j][4] (slab index = w) so gru reads ushort4/slot.
__global__ __launch_bounds__(256, 2) void msg_mfma(const float* __restrict__ out,
                                                   const float* __restrict__ ea_s,
                                                   const float* __restrict__ w1g,
                                                   const float* __restrict__ b1g,
                                                   const unsigned short* __restrict__ bsw,
                                                   const int* __restrict__ src_s,
                                                   unsigned short* __restrict__ msgp, int E) {
    __shared__ __align__(16) unsigned short hs16[128 * EPB];   // 24.6 KB
    __shared__ __align__(16) float w1l[8 * 128];               // 4 KB
    __shared__ __align__(16) float b1l[128];
    const int tid = threadIdx.x;
    const int w = tid >> 6, l = tid & 63;
    const int e0 = blockIdx.x * EPB;
    const int r16 = l & 15, q = l >> 4;

    // stage W1 + b1 into LDS
    {
        f32x4 v = *(const f32x4*)&w1g[tid * 4];
        *(f32x4*)&w1l[tid * 4] = v;
        if (tid < 32) *(f32x4*)&b1l[tid * 4] = *(const f32x4*)&b1g[tid * 4];
    }

    // A rows in fp16 (issue the src gathers EARLY so they overlap the MLP phase)
    f16x8 sfrag[TS][2];
#pragma unroll
    for (int t = 0; t < TS; ++t) {
        int e = e0 + t * 16 + r16;
        int src = (e < E) ? src_s[e] : 0;
        const f32x4* p = (const f32x4*)(out + (size_t)src * 64);
#pragma unroll
        for (int st = 0; st < 2; ++st) {
            f16x8 f = {};
            if (e < E) {
                f32x4 a = p[st * 8 + q * 2], b = p[st * 8 + q * 2 + 1];
#pragma unroll
                for (int j = 0; j < 4; ++j) { f[j] = (_Float16)a[j]; f[4 + j] = (_Float16)b[j]; }
            }
            sfrag[t][st] = f;
        }
    }

    __syncthreads();   // w1l/b1l ready

    // in-kernel edge MLP: thread t<192 computes h[e'=t>>1][koff..koff+64)
    if (tid < 192) {
        int ep = tid >> 1;
        int koff = (tid & 1) * 64;
        int e = e0 + ep;
        bool v = e < E;
        float ear[8];
        const float* earow = ea_s + (size_t)(v ? e : 0) * 8;
#pragma unroll
        for (int i = 0; i < 8; ++i) ear[i] = earow[i];
#pragma unroll
        for (int kv = 0; kv < 16; ++kv) {
            int k = koff + kv * 4;
            f32x4 a = *(const f32x4*)&b1l[k];
#pragma unroll
            for (int i = 0; i < 8; ++i) {
                f32x4 wv = *(const f32x4*)&w1l[i * 128 + k];
                a += ear[i] * wv;
            }
#pragma unroll
            for (int jj = 0; jj < 4; ++jj)
                hs16[(k + jj) * EPB + ep] = v ? f2h(fmaxf(a[jj], 0.f)) : (unsigned short)0;
        }
    }

    // first B buffer (k = w) before barrier to overlap staging latency
    const f16x8* bp = (const f16x8*)bsw;
    f16x8 bfA[8], bfB[8];
#pragma unroll
    for (int i = 0; i < 8; ++i) bfA[i] = bp[((w * 8 + i) << 6) + l];

    __syncthreads();   // hs16 ready

    f32x4 acc[TS][4] = {};

#define MSG_COMPUTE(K, BF)                                                     \
    {                                                                          \
        _Pragma("unroll")                                                      \
        for (int t = 0; t < TS; ++t) {                                         \
            unsigned int hu = hs16[(K) * EPB + t * 16 + r16];                  \
            _Pragma("unroll")                                                  \
            for (int st = 0; st < 2; ++st) {                                   \
                F16x8U s_, a_;                                                 \
                s_.v = sfrag[t][st];                                           \
                asm("v_pk_mul_f16 %0, %1, %2 op_sel:[0,0] op_sel_hi:[0,1]"     \
                    : "=v"(a_.u[0]) : "v"(hu), "v"(s_.u[0]));                  \
                asm("v_pk_mul_f16 %0, %1, %2 op_sel:[0,0] op_sel_hi:[0,1]"     \
                    : "=v"(a_.u[1]) : "v"(hu), "v"(s_.u[1]));                  \
                asm("v_pk_mul_f16 %0, %1, %2 op_sel:[0,0] op_sel_hi:[0,1]"     \
                    : "=v"(a_.u[2]) : "v"(hu), "v"(s_.u[2]));                  \
                asm("v_pk_mul_f16 %0, %1, %2 op_sel:[0,0] op_sel_hi:[0,1]"     \
                    : "=v"(a_.u[3]) : "v"(hu), "v"(s_.u[3]));                  \
                _Pragma("unroll")                                              \
                for (int oc = 0; oc < 4; ++oc)                                 \
                    acc[t][oc] = __builtin_amdgcn_mfma_f32_16x16x32_f16(       \
                        a_.v, BF[st * 4 + oc], acc[t][oc], 0, 0, 0);           \
            }                                                                  \
        }                                                                      \
    }

#pragma unroll 1
    for (int kk = 0; kk < 16; ++kk) {
        int k1 = w + kk * 8;
        int k2 = k1 + 4;
#pragma unroll
        for (int i = 0; i < 8; ++i) bfB[i] = bp[((k2 * 8 + i) << 6) + l];
        MSG_COMPUTE(k1, bfA);
        if (kk < 15) {
            int k3 = k1 + 8;
#pragma unroll
            for (int i = 0; i < 8; ++i) bfA[i] = bp[((k3 * 8 + i) << 6) + l];
        }
        MSG_COMPUTE(k2, bfB);
    }
#undef MSG_COMPUTE

    // bias pseudo-slot k=128 (h = 1): A = sfrag directly, wave 0 only
    if (w == 0) {
#pragma unroll
        for (int i = 0; i < 8; ++i) bfA[i] = bp[((128 * 8 + i) << 6) + l];
#pragma unroll
        for (int t = 0; t < TS; ++t)
#pragma unroll
            for (int st = 0; st < 2; ++st)
#pragma unroll
                for (int oc = 0; oc < 4; ++oc)
                    acc[t][oc] = __builtin_amdgcn_mfma_f32_16x16x32_f16(
                        sfrag[t][st], bfA[st * 4 + oc], acc[t][oc], 0, 0, 0);
    }

    // interleaved fp16 stores: msgp[slot][j][4], slab index = w (NO atomics/reduce)
#pragma unroll
    for (int t = 0; t < TS; ++t) {
#pragma unroll
        for (int r = 0; r < 4; ++r) {
            int e = e0 + t * 16 + q * 4 + r;
            if (e < E) {
                unsigned short* row = msgp + (size_t)e * 256 + r16 * 4 + w;
                row[0]       = f2h(acc[t][0][r]);
                row[16 * 4]  = f2h(acc[t][1][r]);
                row[32 * 4]  = f2h(acc[t][2][r]);
                row[48 * 4]  = f2h(acc[t][3][r]);
            }
        }
    }
}

// ---- gru: aggregate msgp over dst run; m = relu(msum/deg + out@root_w + root_b); GRU
__global__ __launch_bounds__(256) void gru_kernel(float* __restrict__ out,
                                                  const unsigned short* __restrict__ msgp,
                                                  const int* __restrict__ cstart,
                                                  const int* __restrict__ cnt,
                                                  const float* __restrict__ deg,
                                                  const float* __restrict__ root_w,
                                                  const float* __restrict__ root_b,
                                                  const float* __restrict__ wih,
                                                  const float* __restrict__ whh,
                                                  const float* __restrict__ bih,
                                                  const float* __restrict__ bhh) {
    int w = threadIdx.x >> 6, j = threadIdx.x & 63;
    int n = blockIdx.x * 4 + w;            // N divisible by 4
    __shared__ float s_o[4][64];
    __shared__ float s_m[4][64];
    s_o[w][j] = out[(size_t)n * 64 + j];
    __syncthreads();

    // aggregate messages: one ushort4 per slot (4 k-partial slabs interleaved)
    float msum = 0.f;
    {
        int base = cstart[n], c = cnt[n];
        const ushort4* mp4 = (const ushort4*)msgp;
        for (int s2 = 0; s2 < c; ++s2) {
            ushort4 v = mp4[(size_t)(base + s2) * 64 + j];
            msum += (h2f(v.x) + h2f(v.y)) + (h2f(v.z) + h2f(v.w));
        }
    }
    float d = deg[n]; if (d < 1.f) d = 1.f;
    float mv = msum / d + root_b[j];
#pragma unroll 8
    for (int i = 0; i < 64; i++) mv += s_o[w][i] * root_w[i * 64 + j];
    mv = fmaxf(mv, 0.f);
    s_m[w][j] = mv;
    __syncthreads();
    float gi_r = bih[j], gi_z = bih[64 + j], gi_n = bih[128 + j];
    float gh_r = bhh[j], gh_z = bhh[64 + j], gh_n = bhh[128 + j];
#pragma unroll 4
    for (int i = 0; i < 64; i++) {
        float m = s_m[w][i], hv = s_o[w][i];
        gi_r += m * wih[i * 192 + j];
        gi_z += m * wih[i * 192 + 64 + j];
        gi_n += m * wih[i * 192 + 128 + j];
        gh_r += hv * whh[i * 192 + j];
        gh_z += hv * whh[i * 192 + 64 + j];
        gh_n += hv * whh[i * 192 + 128 + j];
    }
    float r = sigmoidf_(gi_r + gh_r);
    float z = sigmoidf_(gi_z + gh_z);
    float nn = tanhf(gi_n + r * gh_n);
    float hnew = (1.f - z) * nn + z * s_o[w][j];
    out[(size_t)n * 64 + j] = hnew;
}

// ============ fused Set2Set (3 iterations) + output head, one block per graph ======
__global__ __launch_bounds__(256) void s2s_final(const float* __restrict__ out,
                                                 const int* __restrict__ batch,
                                                 const float* __restrict__ wih,
                                                 const float* __restrict__ whh,
                                                 const float* __restrict__ bih,
                                                 const float* __restrict__ bhh,
                                                 const float* __restrict__ w1,
                                                 const float* __restrict__ b1,
                                                 const float* __restrict__ w2,
                                                 const float* __restrict__ b2,
                                                 float* __restrict__ y, int N) {
    int b = blockIdx.x;
    int tid = threadIdx.x;
    int gate = tid >> 6, j = tid & 63;
    __shared__ float s_qs[128];
    __shared__ float s_g[4][64];
    __shared__ float s_h[64];
    __shared__ float s_c[64];
    __shared__ int s_lo, s_hi;
    __shared__ float s_red[4];
    __shared__ float s_rv[4][64];

    if (tid < 128) s_qs[tid] = 0.f;
    if (gate == 2) s_h[j] = 0.f;
    if (gate == 3) s_c[j] = 0.f;
    if (tid == 0) {
        int lo = 0, hi = N;
        while (lo < hi) { int mid = (lo + hi) >> 1; if (batch[mid] < b) lo = mid + 1; else hi = mid; }
        s_lo = lo;
        int lo2 = lo, hi2 = N;
        while (lo2 < hi2) { int mid = (lo2 + hi2) >> 1; if (batch[mid] < b + 1) lo2 = mid + 1; else hi2 = mid; }
        s_hi = lo2;
    }
    __syncthreads();

    for (int it = 0; it < 3; ++it) {
        float g = bih[gate * 64 + j] + bhh[gate * 64 + j];
#pragma unroll 4
        for (int i = 0; i < 128; ++i) g += s_qs[i] * wih[i * 256 + gate * 64 + j];
#pragma unroll 4
        for (int i = 0; i < 64; ++i) g += s_h[i] * whh[i * 256 + gate * 64 + j];
        s_g[gate][j] = g;
        __syncthreads();
        if (gate == 0) {
            float c = sigmoidf_(s_g[1][j]) * s_c[j] + sigmoidf_(s_g[0][j]) * tanhf(s_g[2][j]);
            float h = sigmoidf_(s_g[3][j]) * tanhf(c);
            s_c[j] = c;
            s_h[j] = h;
            s_qs[j] = h;
        }
        __syncthreads();

        int lo = s_lo, hi = s_hi;
        float wmax = -3.402823e38f;
        for (int n = lo + gate; n < hi; n += 4) {
            float p = out[(size_t)n * 64 + j] * s_h[j];
#pragma unroll
            for (int d = 32; d >= 1; d >>= 1) p += __shfl_xor(p, d);
            wmax = fmaxf(wmax, p);
        }
        if (j == 0) s_red[gate] = wmax;
        __syncthreads();
        float m = fmaxf(fmaxf(s_red[0], s_red[1]), fmaxf(s_red[2], s_red[3]));
        __syncthreads();
        float ssum = 0.f, rv = 0.f;
        for (int n = lo + gate; n < hi; n += 4) {
            float xv = out[(size_t)n * 64 + j];
            float p = xv * s_h[j];
#pragma unroll
            for (int d = 32; d >= 1; d >>= 1) p += __shfl_xor(p, d);
            float a = expf(p - m);
            ssum += a;
            rv += a * xv;
        }
        if (j == 0) s_red[gate] = ssum;
        s_rv[gate][j] = rv;
        __syncthreads();
        if (gate == 0) {
            float S = s_red[0] + s_red[1] + s_red[2] + s_red[3];
            float r = s_rv[0][j] + s_rv[1][j] + s_rv[2][j] + s_rv[3][j];
            s_qs[64 + j] = (S > 0.f) ? r / S : 0.f;
        }
        __syncthreads();
    }

    if (gate == 0) {
        float tv = b1[j];
#pragma unroll 4
        for (int i = 0; i < 128; ++i) tv += s_qs[i] * w1[i * 64 + j];
        tv = fmaxf(tv, 0.f);
        float p = tv * w2[j];
#pragma unroll
        for (int d = 32; d >= 1; d >>= 1) p += __shfl_xor(p, d);
        if (j == 0) y[b] = p + b2[0];
    }
}

extern "C" void kernel_launch(void* const* d_in, const int* in_sizes, int n_in,
                              void* d_out, int out_size, void* d_ws, size_t ws_size,
                              hipStream_t stream) {
    const int N = N_NODES, E = N_EDGES, B = N_BATCH;
    const float* x       = (const float*)d_in[0];
    const int*   ei      = (const int*)d_in[1];
    const float* ea      = (const float*)d_in[2];
    const int*   batch   = (const int*)d_in[3];
    const float* lin0_w  = (const float*)d_in[4];
    const float* lin0_b  = (const float*)d_in[5];
    const float* nn1_w   = (const float*)d_in[6];
    const float* nn1_b   = (const float*)d_in[7];
    const float* nn2_w   = (const float*)d_in[8];
    const float* nn2_b   = (const float*)d_in[9];
    const float* root_w  = (const float*)d_in[10];
    const float* root_b  = (const float*)d_in[11];
    const float* gru_wih = (const float*)d_in[12];
    const float* gru_whh = (const float*)d_in[13];
    const float* gru_bih = (const float*)d_in[14];
    const float* gru_bhh = (const float*)d_in[15];
    const float* lstm_wih = (const float*)d_in[16];
    const float* lstm_whh = (const float*)d_in[17];
    const float* lstm_bih = (const float*)d_in[18];
    const float* lstm_bhh = (const float*)d_in[19];
    const float* lin1_w  = (const float*)d_in[20];
    const float* lin1_b  = (const float*)d_in[21];
    const float* lin2_w  = (const float*)d_in[22];
    const float* lin2_b  = (const float*)d_in[23];
    float* y = (float*)d_out;

    char* ws = (char*)d_ws;
    size_t off = 0;
    auto alloc = [&](size_t bytes) { void* p = ws + off; off = (off + bytes + 255) & ~(size_t)255; return p; };
    unsigned short* bsw  = (unsigned short*)alloc((size_t)66048 * 8 * 2);    // 1.06 MB fp16
    unsigned short* msgp = (unsigned short*)alloc((size_t)ECAP * 256 * 2);   // 51.2 MB fp16 interleaved
    float* ea_s   = (float*)alloc((size_t)ECAP * 8 * 4);                     // 3.2 MB (sorted)
    float* out    = (float*)alloc((size_t)N * 64 * 4);                       // 5.12 MB
    float* deg    = (float*)alloc((size_t)N * 4);
    int*   cnt    = (int*)alloc((size_t)N * 4);
    int*   cstart = (int*)alloc((size_t)N * 4);
    int*   cursor = (int*)alloc((size_t)N * 4);
    int*   src_s  = (int*)alloc((size_t)E * 4);

    hipMemsetAsync(cnt, 0, (size_t)N * 4, stream);

    prep1_kernel<<<LIN0_BLOCKS + BSW_BLOCKS + CNT_BLOCKS, 256, 0, stream>>>(
        x, lin0_w, lin0_b, nn2_w, nn2_b, ei, out, bsw, cnt, E);
    scan_kernel<<<1, 1024, 0, stream>>>(cnt, cstart, cursor, deg, N);
    place_kernel<<<(E + 255) / 256, 256, 0, stream>>>(ei, ea, cursor, src_s, ea_s, E);

    for (int step = 0; step < 3; ++step) {
        msg_mfma<<<(E + EPB - 1) / EPB, 256, 0, stream>>>(out, ea_s, nn1_w, nn1_b,
                                                          bsw, src_s, msgp, E);
        gru_kernel<<<N / 4, 256, 0, stream>>>(out, msgp, cstart, cnt, deg, root_w, root_b,
                                              gru_wih, gru_whh, gru_bih, gru_bhh);
    }

    s2s_final<<<B, 256, 0, stream>>>(out, batch, lstm_wih, lstm_whh, lstm_bih, lstm_bhh,
                                     lin1_w, lin1_b, lin2_w, lin2_b, y, N);
}

// Round 19
// 671.648 us; speedup vs baseline: 1.0333x; 1.0165x over previous
//
#include <hip/hip_runtime.h>
#include <hip/hip_bf16.h>
#include <hip/hip_fp16.h>
#include <cstddef>
#include <cstdint>

#define N_NODES 20000
#define N_EDGES 100000
#define N_BATCH 512

#define EPB 96   // edges per block
#define TS 6     // 16-row M-subtiles per block
#define ECAP 100032  // slot capacity (divisible by 96)

typedef __attribute__((ext_vector_type(8))) short ushort8_t;
typedef __attribute__((ext_vector_type(8))) _Float16 f16x8;
typedef __attribute__((ext_vector_type(4))) float f32x4;

union F16x8U { f16x8 v; unsigned int u[4]; };

__device__ __forceinline__ float sigmoidf_(float x) { return 1.f / (1.f + expf(-x)); }
__device__ __forceinline__ unsigned short f2h(float x) {
    return __half_as_ushort(__float2half(x));
}
__device__ __forceinline__ float h2f(unsigned short s) {
    return __half2float(__ushort_as_half(s));
}

// ============ prep1: lin0 + bsw pack + dst histogram ============
#define LIN0_BLOCKS 5000  // N*64/256
#define BSW_BLOCKS 258
#define CNT_BLOCKS 391    // ceil(E/256)

__global__ __launch_bounds__(256) void prep1_kernel(
        const float* __restrict__ x, const float* __restrict__ l0w, const float* __restrict__ l0b,
        const float* __restrict__ w2, const float* __restrict__ b2,
        const int* __restrict__ ei,
        float* __restrict__ out, unsigned short* __restrict__ bsw,
        int* __restrict__ cnt, int E) {
    int bid = blockIdx.x, tid = threadIdx.x;
    if (bid < LIN0_BLOCKS) {
        int idx = bid * 256 + tid;   // n*64 + j
        int n = idx >> 6, j = idx & 63;
        float acc = l0b[j];
#pragma unroll
        for (int i = 0; i < 16; i++) acc += x[n * 16 + i] * l0w[i * 64 + j];
        out[idx] = fmaxf(acc, 0.f);
    } else if (bid < LIN0_BLOCKS + BSW_BLOCKS) {
        int idx = (bid - LIN0_BLOCKS) * 256 + tid;
        if (idx < 66048) {
            int l = idx & 63, oc = (idx >> 6) & 3, ks = idx >> 8;
            int o = oc * 16 + (l & 15);
            int kap0 = ks * 32 + 8 * (l >> 4);
#pragma unroll
            for (int j = 0; j < 8; ++j) {
                int kap = kap0 + j;
                int k = kap >> 6, i = kap & 63;
                float v = (k < 128) ? w2[(size_t)k * 4096 + i * 64 + o] : b2[i * 64 + o];
                bsw[(size_t)idx * 8 + j] = f2h(v);
            }
        }
    } else {
        int e = (bid - LIN0_BLOCKS - BSW_BLOCKS) * 256 + tid;
        if (e < E) atomicAdd(&cnt[ei[E + e]], 1);
    }
}

// ============ prep2: exclusive scan of cnt -> cstart, cursor; deg float ============
__global__ __launch_bounds__(1024) void scan_kernel(const int* __restrict__ cnt,
                                                    int* __restrict__ cstart,
                                                    int* __restrict__ cursor,
                                                    float* __restrict__ degf, int n) {
    __shared__ int part[1024];
    int t = threadIdx.x;
    int base = t * 20;
    int loc[20];
    int s = 0;
#pragma unroll
    for (int i = 0; i < 20; ++i) {
        int idx = base + i;
        int c = (idx < n) ? cnt[idx] : 0;
        loc[i] = s;
        s += c;
    }
    part[t] = s;
    __syncthreads();
    for (int off = 1; off < 1024; off <<= 1) {
        int v = (t >= off) ? part[t - off] : 0;
        __syncthreads();
        part[t] += v;
        __syncthreads();
    }
    int tb = part[t] - s;   // exclusive base
#pragma unroll
    for (int i = 0; i < 20; ++i) {
        int idx = base + i;
        if (idx < n) {
            int b0 = tb + loc[i];
            cstart[idx] = b0;
            cursor[idx] = b0;
            degf[idx] = (float)cnt[idx];
        }
    }
}

// ============ prep3: bucket-place edges sorted by dst (also permutes edge_attr) ====
__global__ void place_kernel(const int* __restrict__ ei, const float* __restrict__ ea,
                             int* __restrict__ cursor,
                             int* __restrict__ src_s, float* __restrict__ ea_s, int E) {
    int e = blockIdx.x * 256 + threadIdx.x;
    if (e < E) {
        int dst = ei[E + e];
        int slot = atomicAdd(&cursor[dst], 1);
        src_s[slot] = ei[e];
        const float4* s = (const float4*)(ea + (size_t)e * 8);
        float4 a = s[0], b = s[1];
        float4* d = (float4*)(ea_s + (size_t)slot * 8);
        d[0] = a; d[1] = b;
    }
}

// ============ fused NNConv message, fp16 MFMA 16x16x32, dst-sorted edges ============
// In-kernel edge MLP: h = relu(ea_s @ W1 + b1) computed into LDS (no hb buffer).
// msg[e,:] = sum_k (h[e,k]*s_e) @ B_k + s_e @ b2v  (bias = pseudo-slot k==128, h=1)
// 4 waves/block, k split across waves; wave w plain-stores fp16 k-partial slab.
__global__ __launch_bounds__(256, 2) void msg_mfma(const float* __restrict__ out,
                                                   const float* __restrict__ ea_s,
                                                   const float* __restrict__ w1g,
                                                   const float* __restrict__ b1g,
                                                   const unsigned short* __restrict__ bsw,
                                                   const int* __restrict__ src_s,
                                                   unsigned short* __restrict__ msgp, int E) {
    __shared__ __align__(16) unsigned short hs16[128 * EPB];   // 24.6 KB
    __shared__ __align__(16) float w1l[8 * 128];               // 4 KB
    __shared__ __align__(16) float b1l[128];
    const int tid = threadIdx.x;
    const int w = tid >> 6, l = tid & 63;
    const int e0 = blockIdx.x * EPB;
    const int r16 = l & 15, q = l >> 4;

    // stage W1 + b1 into LDS
    {
        f32x4 v = *(const f32x4*)&w1g[tid * 4];
        *(f32x4*)&w1l[tid * 4] = v;
        if (tid < 32) *(f32x4*)&b1l[tid * 4] = *(const f32x4*)&b1g[tid * 4];
    }

    // A rows in fp16: sfrag[t][st] = fp16(out[src[e]][st*32 + q*8 .. +8])
    // (issued EARLY so the L2 gather latency overlaps the MLP phase)
    f16x8 sfrag[TS][2];
#pragma unroll
    for (int t = 0; t < TS; ++t) {
        int e = e0 + t * 16 + r16;
        int src = (e < E) ? src_s[e] : 0;
        const f32x4* p = (const f32x4*)(out + (size_t)src * 64);
#pragma unroll
        for (int st = 0; st < 2; ++st) {
            f16x8 f = {};
            if (e < E) {
                f32x4 a = p[st * 8 + q * 2], b = p[st * 8 + q * 2 + 1];
#pragma unroll
                for (int j = 0; j < 4; ++j) { f[j] = (_Float16)a[j]; f[4 + j] = (_Float16)b[j]; }
            }
            sfrag[t][st] = f;
        }
    }

    __syncthreads();   // w1l/b1l ready

    // in-kernel edge MLP: thread t<192 computes h[e'=t>>1][koff..koff+64)
    if (tid < 192) {
        int ep = tid >> 1;
        int koff = (tid & 1) * 64;
        int e = e0 + ep;
        bool v = e < E;
        float ear[8];
        const float* earow = ea_s + (size_t)(v ? e : 0) * 8;
#pragma unroll
        for (int i = 0; i < 8; ++i) ear[i] = earow[i];
#pragma unroll
        for (int kv = 0; kv < 16; ++kv) {
            int k = koff + kv * 4;
            f32x4 a = *(const f32x4*)&b1l[k];
#pragma unroll
            for (int i = 0; i < 8; ++i) {
                f32x4 wv = *(const f32x4*)&w1l[i * 128 + k];
                a += ear[i] * wv;
            }
#pragma unroll
            for (int jj = 0; jj < 4; ++jj)
                hs16[(k + jj) * EPB + ep] = v ? f2h(fmaxf(a[jj], 0.f)) : (unsigned short)0;
        }
    }

    // first B buffer (k = w) before barrier to overlap staging latency
    const f16x8* bp = (const f16x8*)bsw;
    f16x8 bfA[8], bfB[8];
#pragma unroll
    for (int i = 0; i < 8; ++i) bfA[i] = bp[((w * 8 + i) << 6) + l];

    __syncthreads();   // hs16 ready

    f32x4 acc[TS][4] = {};

#define MSG_COMPUTE(K, BF)                                                     \
    {                                                                          \
        _Pragma("unroll")                                                      \
        for (int t = 0; t < TS; ++t) {                                         \
            unsigned int hu = hs16[(K) * EPB + t * 16 + r16];                  \
            _Pragma("unroll")                                                  \
            for (int st = 0; st < 2; ++st) {                                   \
                F16x8U s_, a_;                                                 \
                s_.v = sfrag[t][st];                                           \
                asm("v_pk_mul_f16 %0, %1, %2 op_sel:[0,0] op_sel_hi:[0,1]"     \
                    : "=v"(a_.u[0]) : "v"(hu), "v"(s_.u[0]));                  \
                asm("v_pk_mul_f16 %0, %1, %2 op_sel:[0,0] op_sel_hi:[0,1]"     \
                    : "=v"(a_.u[1]) : "v"(hu), "v"(s_.u[1]));                  \
                asm("v_pk_mul_f16 %0, %1, %2 op_sel:[0,0] op_sel_hi:[0,1]"     \
                    : "=v"(a_.u[2]) : "v"(hu), "v"(s_.u[2]));                  \
                asm("v_pk_mul_f16 %0, %1, %2 op_sel:[0,0] op_sel_hi:[0,1]"     \
                    : "=v"(a_.u[3]) : "v"(hu), "v"(s_.u[3]));                  \
                _Pragma("unroll")                                              \
                for (int oc = 0; oc < 4; ++oc)                                 \
                    acc[t][oc] = __builtin_amdgcn_mfma_f32_16x16x32_f16(       \
                        a_.v, BF[st * 4 + oc], acc[t][oc], 0, 0, 0);           \
            }                                                                  \
        }                                                                      \
    }

#pragma unroll 1
    for (int kk = 0; kk < 16; ++kk) {
        int k1 = w + kk * 8;
        int k2 = k1 + 4;
#pragma unroll
        for (int i = 0; i < 8; ++i) bfB[i] = bp[((k2 * 8 + i) << 6) + l];
        MSG_COMPUTE(k1, bfA);
        if (kk < 15) {
            int k3 = k1 + 8;
#pragma unroll
            for (int i = 0; i < 8; ++i) bfA[i] = bp[((k3 * 8 + i) << 6) + l];
        }
        MSG_COMPUTE(k2, bfB);
    }
#undef MSG_COMPUTE

    // bias pseudo-slot k=128 (h = 1): A = sfrag directly, wave 0 only
    if (w == 0) {
#pragma unroll
        for (int i = 0; i < 8; ++i) bfA[i] = bp[((128 * 8 + i) << 6) + l];
#pragma unroll
        for (int t = 0; t < TS; ++t)
#pragma unroll
            for (int st = 0; st < 2; ++st)
#pragma unroll
                for (int oc = 0; oc < 4; ++oc)
                    acc[t][oc] = __builtin_amdgcn_mfma_f32_16x16x32_f16(
                        sfrag[t][st], bfA[st * 4 + oc], acc[t][oc], 0, 0, 0);
    }

    // plain coalesced fp16 stores of this wave's k-partial slab (NO atomics, NO reduce)
    unsigned short* slab = msgp + (size_t)w * ECAP * 64;
#pragma unroll
    for (int t = 0; t < TS; ++t) {
#pragma unroll
        for (int r = 0; r < 4; ++r) {
            int e = e0 + t * 16 + q * 4 + r;
            if (e < E) {
                unsigned short* row = slab + (size_t)e * 64 + r16;
                row[0]  = f2h(acc[t][0][r]);
                row[16] = f2h(acc[t][1][r]);
                row[32] = f2h(acc[t][2][r]);
                row[48] = f2h(acc[t][3][r]);
            }
        }
    }
}

// ---- gru: aggregate msgp over dst run; m = relu(msum/deg + out@root_w + root_b); GRU
__global__ __launch_bounds__(256) void gru_kernel(float* __restrict__ out,
                                                  const unsigned short* __restrict__ msgp,
                                                  const int* __restrict__ cstart,
                                                  const int* __restrict__ cnt,
                                                  const float* __restrict__ deg,
                                                  const float* __restrict__ root_w,
                                                  const float* __restrict__ root_b,
                                                  const float* __restrict__ wih,
                                                  const float* __restrict__ whh,
                                                  const float* __restrict__ bih,
                                                  const float* __restrict__ bhh) {
    int w = threadIdx.x >> 6, j = threadIdx.x & 63;
    int n = blockIdx.x * 4 + w;            // N divisible by 4
    __shared__ float s_o[4][64];
    __shared__ float s_m[4][64];
    s_o[w][j] = out[(size_t)n * 64 + j];
    __syncthreads();

    // aggregate messages: sum 4 k-partial slabs over this node's slot run
    float msum = 0.f;
    {
        int base = cstart[n], c = cnt[n];
        for (int s2 = 0; s2 < c; ++s2) {
            size_t slot = (size_t)(base + s2) * 64 + j;
            float a0 = h2f(msgp[slot]);
            float a1 = h2f(msgp[(size_t)ECAP * 64 + slot]);
            float a2 = h2f(msgp[2 * (size_t)ECAP * 64 + slot]);
            float a3 = h2f(msgp[3 * (size_t)ECAP * 64 + slot]);
            msum += (a0 + a1) + (a2 + a3);
        }
    }
    float d = deg[n]; if (d < 1.f) d = 1.f;
    float mv = msum / d + root_b[j];
#pragma unroll 8
    for (int i = 0; i < 64; i++) mv += s_o[w][i] * root_w[i * 64 + j];
    mv = fmaxf(mv, 0.f);
    s_m[w][j] = mv;
    __syncthreads();
    float gi_r = bih[j], gi_z = bih[64 + j], gi_n = bih[128 + j];
    float gh_r = bhh[j], gh_z = bhh[64 + j], gh_n = bhh[128 + j];
#pragma unroll 4
    for (int i = 0; i < 64; i++) {
        float m = s_m[w][i], hv = s_o[w][i];
        gi_r += m * wih[i * 192 + j];
        gi_z += m * wih[i * 192 + 64 + j];
        gi_n += m * wih[i * 192 + 128 + j];
        gh_r += hv * whh[i * 192 + j];
        gh_z += hv * whh[i * 192 + 64 + j];
        gh_n += hv * whh[i * 192 + 128 + j];
    }
    float r = sigmoidf_(gi_r + gh_r);
    float z = sigmoidf_(gi_z + gh_z);
    float nn = tanhf(gi_n + r * gh_n);
    float hnew = (1.f - z) * nn + z * s_o[w][j];
    out[(size_t)n * 64 + j] = hnew;
}

// ============ fused Set2Set (3 iterations) + output head, one block per graph ======
__global__ __launch_bounds__(256) void s2s_final(const float* __restrict__ out,
                                                 const int* __restrict__ batch,
                                                 const float* __restrict__ wih,
                                                 const float* __restrict__ whh,
                                                 const float* __restrict__ bih,
                                                 const float* __restrict__ bhh,
                                                 const float* __restrict__ w1,
                                                 const float* __restrict__ b1,
                                                 const float* __restrict__ w2,
                                                 const float* __restrict__ b2,
                                                 float* __restrict__ y, int N) {
    int b = blockIdx.x;
    int tid = threadIdx.x;
    int gate = tid >> 6, j = tid & 63;
    __shared__ float s_qs[128];
    __shared__ float s_g[4][64];
    __shared__ float s_h[64];
    __shared__ float s_c[64];
    __shared__ int s_lo, s_hi;
    __shared__ float s_red[4];
    __shared__ float s_rv[4][64];

    if (tid < 128) s_qs[tid] = 0.f;
    if (gate == 2) s_h[j] = 0.f;
    if (gate == 3) s_c[j] = 0.f;
    if (tid == 0) {
        int lo = 0, hi = N;
        while (lo < hi) { int mid = (lo + hi) >> 1; if (batch[mid] < b) lo = mid + 1; else hi = mid; }
        s_lo = lo;
        int lo2 = lo, hi2 = N;
        while (lo2 < hi2) { int mid = (lo2 + hi2) >> 1; if (batch[mid] < b + 1) lo2 = mid + 1; else hi2 = mid; }
        s_hi = lo2;
    }
    __syncthreads();

    for (int it = 0; it < 3; ++it) {
        float g = bih[gate * 64 + j] + bhh[gate * 64 + j];
#pragma unroll 4
        for (int i = 0; i < 128; ++i) g += s_qs[i] * wih[i * 256 + gate * 64 + j];
#pragma unroll 4
        for (int i = 0; i < 64; ++i) g += s_h[i] * whh[i * 256 + gate * 64 + j];
        s_g[gate][j] = g;
        __syncthreads();
        if (gate == 0) {
            float c = sigmoidf_(s_g[1][j]) * s_c[j] + sigmoidf_(s_g[0][j]) * tanhf(s_g[2][j]);
            float h = sigmoidf_(s_g[3][j]) * tanhf(c);
            s_c[j] = c;
            s_h[j] = h;
            s_qs[j] = h;
        }
        __syncthreads();

        int lo = s_lo, hi = s_hi;
        float wmax = -3.402823e38f;
        for (int n = lo + gate; n < hi; n += 4) {
            float p = out[(size_t)n * 64 + j] * s_h[j];
#pragma unroll
            for (int d = 32; d >= 1; d >>= 1) p += __shfl_xor(p, d);
            wmax = fmaxf(wmax, p);
        }
        if (j == 0) s_red[gate] = wmax;
        __syncthreads();
        float m = fmaxf(fmaxf(s_red[0], s_red[1]), fmaxf(s_red[2], s_red[3]));
        __syncthreads();
        float ssum = 0.f, rv = 0.f;
        for (int n = lo + gate; n < hi; n += 4) {
            float xv = out[(size_t)n * 64 + j];
            float p = xv * s_h[j];
#pragma unroll
            for (int d = 32; d >= 1; d >>= 1) p += __shfl_xor(p, d);
            float a = expf(p - m);
            ssum += a;
            rv += a * xv;
        }
        if (j == 0) s_red[gate] = ssum;
        s_rv[gate][j] = rv;
        __syncthreads();
        if (gate == 0) {
            float S = s_red[0] + s_red[1] + s_red[2] + s_red[3];
            float r = s_rv[0][j] + s_rv[1][j] + s_rv[2][j] + s_rv[3][j];
            s_qs[64 + j] = (S > 0.f) ? r / S : 0.f;
        }
        __syncthreads();
    }

    if (gate == 0) {
        float tv = b1[j];
#pragma unroll 4
        for (int i = 0; i < 128; ++i) tv += s_qs[i] * w1[i * 64 + j];
        tv = fmaxf(tv, 0.f);
        float p = tv * w2[j];
#pragma unroll
        for (int d = 32; d >= 1; d >>= 1) p += __shfl_xor(p, d);
        if (j == 0) y[b] = p + b2[0];
    }
}

extern "C" void kernel_launch(void* const* d_in, const int* in_sizes, int n_in,
                              void* d_out, int out_size, void* d_ws, size_t ws_size,
                              hipStream_t stream) {
    const int N = N_NODES, E = N_EDGES, B = N_BATCH;
    const float* x       = (const float*)d_in[0];
    const int*   ei      = (const int*)d_in[1];
    const float* ea      = (const float*)d_in[2];
    const int*   batch   = (const int*)d_in[3];
    const float* lin0_w  = (const float*)d_in[4];
    const float* lin0_b  = (const float*)d_in[5];
    const float* nn1_w   = (const float*)d_in[6];
    const float* nn1_b   = (const float*)d_in[7];
    const float* nn2_w   = (const float*)d_in[8];
    const float* nn2_b   = (const float*)d_in[9];
    const float* root_w  = (const float*)d_in[10];
    const float* root_b  = (const float*)d_in[11];
    const float* gru_wih = (const float*)d_in[12];
    const float* gru_whh = (const float*)d_in[13];
    const float* gru_bih = (const float*)d_in[14];
    const float* gru_bhh = (const float*)d_in[15];
    const float* lstm_wih = (const float*)d_in[16];
    const float* lstm_whh = (const float*)d_in[17];
    const float* lstm_bih = (const float*)d_in[18];
    const float* lstm_bhh = (const float*)d_in[19];
    const float* lin1_w  = (const float*)d_in[20];
    const float* lin1_b  = (const float*)d_in[21];
    const float* lin2_w  = (const float*)d_in[22];
    const float* lin2_b  = (const float*)d_in[23];
    float* y = (float*)d_out;

    char* ws = (char*)d_ws;
    size_t off = 0;
    auto alloc = [&](size_t bytes) { void* p = ws + off; off = (off + bytes + 255) & ~(size_t)255; return p; };
    unsigned short* bsw  = (unsigned short*)alloc((size_t)66048 * 8 * 2);    // 1.06 MB fp16
    unsigned short* msgp = (unsigned short*)alloc((size_t)4 * ECAP * 64 * 2);// 51.2 MB fp16
    float* ea_s   = (float*)alloc((size_t)ECAP * 8 * 4);                     // 3.2 MB (sorted)
    float* out    = (float*)alloc((size_t)N * 64 * 4);                       // 5.12 MB
    float* deg    = (float*)alloc((size_t)N * 4);
    int*   cnt    = (int*)alloc((size_t)N * 4);
    int*   cstart = (int*)alloc((size_t)N * 4);
    int*   cursor = (int*)alloc((size_t)N * 4);
    int*   src_s  = (int*)alloc((size_t)E * 4);

    hipMemsetAsync(cnt, 0, (size_t)N * 4, stream);

    prep1_kernel<<<LIN0_BLOCKS + BSW_BLOCKS + CNT_BLOCKS, 256, 0, stream>>>(
        x, lin0_w, lin0_b, nn2_w, nn2_b, ei, out, bsw, cnt, E);
    scan_kernel<<<1, 1024, 0, stream>>>(cnt, cstart, cursor, deg, N);
    place_kernel<<<(E + 255) / 256, 256, 0, stream>>>(ei, ea, cursor, src_s, ea_s, E);

    for (int step = 0; step < 3; ++step) {
        msg_mfma<<<(E + EPB - 1) / EPB, 256, 0, stream>>>(out, ea_s, nn1_w, nn1_b,
                                                          bsw, src_s, msgp, E);
        gru_kernel<<<N / 4, 256, 0, stream>>>(out, msgp, cstart, cnt, deg, root_w, root_b,
                                              gru_wih, gru_whh, gru_bih, gru_bhh);
    }

    s2s_final<<<B, 256, 0, stream>>>(out, batch, lstm_wih, lstm_whh, lstm_bih, lstm_bhh,
                                     lin1_w, lin1_b, lin2_w, lin2_b, y, N);
}